// Round 6
// baseline (95.932 us; speedup 1.0000x reference)
//
#include <hip/hip_runtime.h>
#include <hip/hip_bf16.h>
#include <stdint.h>

#define N_IN 195
#define N_OUT 778
#define D_IN 256
#define D_OUTC 128
#define NS 9
#define KTOT 2304          // NS * D_IN
#define MM 49792           // 64 * 778 = 389 * 128, no tail
#define BM 128
#define BK 128
#define NWG 389
#define POOL_BLOCKS 12448  // MM / 4
#define WT_BLOCKS 1152     // 128*2304/256

using short8  = __attribute__((ext_vector_type(8))) short;
using short4v = __attribute__((ext_vector_type(4))) short;
using f32x4   = __attribute__((ext_vector_type(4))) float;

__device__ __forceinline__ void gload16(const void* g, void* l) {
  __builtin_amdgcn_global_load_lds(
      (const __attribute__((address_space(1))) uint32_t*)g,
      (__attribute__((address_space(3))) uint32_t*)l, 16, 0, 0);
}

__device__ __forceinline__ unsigned short f2bf(float f) {  // RNE
  uint32_t u = __float_as_uint(f);
  return (unsigned short)((u + 0x7FFFu + ((u >> 16) & 1u)) >> 16);
}

// ---------------- kernel 1: pool + bf16 convert, fused W-transpose ----------
__global__ __launch_bounds__(256) void prep_kernel(
    const float* __restrict__ x, const int* __restrict__ col,
    const float* __restrict__ value, const float* __restrict__ W,
    unsigned short* __restrict__ pooled, unsigned short* __restrict__ Wt) {
  int bid = blockIdx.x;
  if (bid < POOL_BLOCKS) {
    int m = bid * 4 + (threadIdx.x >> 6);
    int lane = threadIdx.x & 63;
    int b = (unsigned)m / N_OUT;
    int n = m - b * N_OUT;
    int j = 3 * n;
    int c0 = col[j], c1 = col[j + 1], c2 = col[j + 2];
    float v0 = value[j], v1 = value[j + 1], v2 = value[j + 2];
    const float4* x0 = (const float4*)(x + ((size_t)b * N_IN + c0) * D_IN);
    const float4* x1 = (const float4*)(x + ((size_t)b * N_IN + c1) * D_IN);
    const float4* x2 = (const float4*)(x + ((size_t)b * N_IN + c2) * D_IN);
    float4 a0 = x0[lane], a1 = x1[lane], a2 = x2[lane];
    short4v pk;
    pk[0] = (short)f2bf(v0 * a0.x + v1 * a1.x + v2 * a2.x);
    pk[1] = (short)f2bf(v0 * a0.y + v1 * a1.y + v2 * a2.y);
    pk[2] = (short)f2bf(v0 * a0.z + v1 * a1.z + v2 * a2.z);
    pk[3] = (short)f2bf(v0 * a0.w + v1 * a1.w + v2 * a2.w);
    ((short4v*)(pooled + (size_t)m * D_IN))[lane] = pk;
  } else {
    int idx = (bid - POOL_BLOCKS) * 256 + threadIdx.x;  // over 128*2304
    int o = idx / KTOT, k = idx - o * KTOT;
    Wt[idx] = f2bf(W[(size_t)k * D_OUTC + o]);
  }
}

// ---------------- kernel 2: gather-GEMM, BK=128 (18 phases) -----------------
// 256 thr = 4 waves; wave tile 64x64 (4x4 frags of 16x16), 16x16x32 MFMA.
// Phase = (spiral s, half h). A,B rows are 256B in LDS, 16-chunk XOR swizzle.
__global__ __launch_bounds__(256) void gemm_kernel(
    const unsigned short* __restrict__ pooled,   // bf16 bits [MM][256]
    const unsigned short* __restrict__ Wt,       // bf16 bits [128][2304]
    const int* __restrict__ indices,
    const float* __restrict__ bias,
    float* __restrict__ out) {
  __shared__ unsigned short Asm[2][BM * BK];     // 2 x 32 KB
  __shared__ unsigned short Bsm[2][D_OUTC * BK]; // 2 x 32 KB  (128 KB total)

  const int tid = threadIdx.x;
  const int wave = tid >> 6, lane = tid & 63;
  const int wr = wave >> 1, wc = wave & 1;       // 2x2 waves of 64x64

  // XCD-aware bijective swizzle (NWG=389: q8=48, r8=5)
  const int xcd = blockIdx.x & 7, loc = blockIdx.x >> 3;
  const int q8 = NWG >> 3, r8 = NWG & 7;
  const int wg = (xcd < r8 ? xcd * (q8 + 1) : r8 * (q8 + 1) + (xcd - r8) * q8) + loc;
  const int bm = wg * BM;

  // staging geometry: 8 instrs each for A and B; instr i covers 4 rows
  // r = wave*32 + i*4 + (lane>>4), chunk (lane&15) of 16x16B = 256B row.
  const int lr4 = lane >> 4;                     // row-in-group 0..3
  const int lc4 = lane & 15;                     // dest chunk 0..15
  int nn[8]; size_t gb[8];
  int asrc[8];                                   // A source elem offset in row-half
  const unsigned short* wtrow[8];
  #pragma unroll
  for (int i = 0; i < 8; ++i) {
    int r = wave * 32 + i * 4 + lr4;             // 0..127
    int m = bm + r;
    int b = (unsigned)m / N_OUT;
    nn[i] = m - b * N_OUT;
    gb[i] = (size_t)b * N_OUT;
    int sc = (lc4 ^ (r & 15)) * 8;               // swizzled source chunk (elems)
    asrc[i] = sc;
    wtrow[i] = Wt + (size_t)r * KTOT + sc;       // B row o == r
  }
  const int ldst = wave * 8192 + lane * 16;      // LDS dest byte (linear)
  char* AsmB = (char*)&Asm[0][0];
  char* BsmB = (char*)&Bsm[0][0];

  // spiral gather indices, current + next
  int gc[8], gn[8];
  #pragma unroll
  for (int i = 0; i < 8; ++i) gc[i] = indices[nn[i] * NS + 0];

  f32x4 acc[4][4];
  #pragma unroll
  for (int i = 0; i < 4; ++i)
    #pragma unroll
    for (int j = 0; j < 4; ++j) acc[i][j] = f32x4{0.f, 0.f, 0.f, 0.f};

  // stage phase (s, h) into buffer buf; g = gather indices for this spiral
  auto stage = [&](int buf, int s, int h, const int* g) {
    const int bofs = buf * 32768;
    const int kq = s * 256 + h * 128;            // global k base for B
    #pragma unroll
    for (int i = 0; i < 8; ++i) {
      const unsigned short* srcA =
          pooled + (((gb[i] + (size_t)g[i]) << 8) + h * 128 + asrc[i]);
      gload16(srcA, AsmB + bofs + i * 1024 + ldst);
      gload16(wtrow[i] + kq, BsmB + bofs + i * 1024 + ldst);
    }
  };

  auto compute = [&](int buf) {
    const char* Ab = AsmB + buf * 32768;
    const char* Bb = BsmB + buf * 32768;
    #pragma unroll
    for (int ks = 0; ks < 4; ++ks) {
      short8 af[4], bf[4];
      const int cb = ks * 64 + (lane >> 4) * 16; // byte col within 256B row
      #pragma unroll
      for (int i = 0; i < 4; ++i) {
        int r = wr * 64 + i * 16 + (lane & 15);
        af[i] = *(const short8*)(Ab + r * 256 + (cb ^ ((r & 15) << 4)));
      }
      #pragma unroll
      for (int j = 0; j < 4; ++j) {
        int o = wc * 64 + j * 16 + (lane & 15);
        bf[j] = *(const short8*)(Bb + o * 256 + (cb ^ ((o & 15) << 4)));
      }
      #pragma unroll
      for (int i = 0; i < 4; ++i)
        #pragma unroll
        for (int j = 0; j < 4; ++j)
          acc[i][j] = __builtin_amdgcn_mfma_f32_16x16x32_bf16(
              af[i], bf[j], acc[i][j], 0, 0, 0);
    }
  };

  // ---- pipeline over 18 phases (9 spirals x 2 halves), R2-proven pattern ---
  stage(0, 0, 0, gc);
  __syncthreads();

  for (int s = 0; s < NS; ++s) {
    if (s < NS - 1) {
      #pragma unroll
      for (int i = 0; i < 8; ++i) gn[i] = indices[nn[i] * NS + s + 1];
    }
    // phase (s,0): prefetch (s,1)
    stage(1, s, 1, gc);
    compute(0);
    __syncthreads();   // drains vmcnt(0): buffer 1 ready for all waves
    // phase (s,1): prefetch (s+1,0)
    if (s < NS - 1) stage(0, s + 1, 0, gn);
    compute(1);
    __syncthreads();
    #pragma unroll
    for (int i = 0; i < 8; ++i) gc[i] = gn[i];
  }

  // ---- epilogue: bias + relu ----
  #pragma unroll
  for (int j = 0; j < 4; ++j) {
    int colo = wc * 64 + j * 16 + (lane & 15);
    float bo = bias[colo];
    #pragma unroll
    for (int i = 0; i < 4; ++i) {
      int rb = bm + wr * 64 + i * 16 + (lane >> 4) * 4;
      #pragma unroll
      for (int q = 0; q < 4; ++q) {
        int row = rb + q;
        out[(size_t)row * D_OUTC + colo] = fmaxf(acc[i][j][q] + bo, 0.f);
      }
    }
  }
}

extern "C" void kernel_launch(void* const* d_in, const int* in_sizes, int n_in,
                              void* d_out, int out_size, void* d_ws, size_t ws_size,
                              hipStream_t stream) {
  const float* x       = (const float*)d_in[0];
  // d_in[1] = row (unused: structure is repeat(arange(N_out),3))
  const int*   col     = (const int*)d_in[2];
  const float* value   = (const float*)d_in[3];
  const int*   indices = (const int*)d_in[4];
  const float* W       = (const float*)d_in[5];
  const float* bias    = (const float*)d_in[6];
  float* out           = (float*)d_out;

  unsigned short* pooled = (unsigned short*)d_ws;
  unsigned short* Wt = (unsigned short*)((char*)d_ws + (size_t)MM * D_IN * 2);

  prep_kernel<<<POOL_BLOCKS + WT_BLOCKS, 256, 0, stream>>>(x, col, value, W,
                                                           pooled, Wt);
  gemm_kernel<<<NWG, 256, 0, stream>>>(pooled, Wt, indices, bias, out);
}

// Round 7
// 62.028 us; speedup vs baseline: 1.5466x; 1.5466x over previous
//
#include <hip/hip_runtime.h>
#include <hip/hip_bf16.h>
#include <stdint.h>

#define N_IN 195
#define N_OUT 778
#define D_IN 256
#define D_OUTC 128
#define NS 9
#define KTOT 2304          // NS * D_IN
#define MM 49792           // 64 * 778 = 389 * 128, no tail
#define BM 128
#define BK 64
#define NWG 389
#define POOL_BLOCKS 12448  // MM / 4
#define WT_BLOCKS 1152     // 128*2304/256

using short8  = __attribute__((ext_vector_type(8))) short;
using short4v = __attribute__((ext_vector_type(4))) short;
using f32x4   = __attribute__((ext_vector_type(4))) float;

__device__ __forceinline__ void gload16(const void* g, void* l) {
  __builtin_amdgcn_global_load_lds(
      (const __attribute__((address_space(1))) uint32_t*)g,
      (__attribute__((address_space(3))) uint32_t*)l, 16, 0, 0);
}

__device__ __forceinline__ unsigned short f2bf(float f) {  // RNE
  uint32_t u = __float_as_uint(f);
  return (unsigned short)((u + 0x7FFFu + ((u >> 16) & 1u)) >> 16);
}

// ---------------- kernel 1: pool + bf16 convert, fused W-transpose ----------
__global__ __launch_bounds__(256) void prep_kernel(
    const float* __restrict__ x, const int* __restrict__ col,
    const float* __restrict__ value, const float* __restrict__ W,
    unsigned short* __restrict__ pooled, unsigned short* __restrict__ Wt) {
  int bid = blockIdx.x;
  if (bid < POOL_BLOCKS) {
    int m = bid * 4 + (threadIdx.x >> 6);
    int lane = threadIdx.x & 63;
    int b = (unsigned)m / N_OUT;
    int n = m - b * N_OUT;
    int j = 3 * n;
    int c0 = col[j], c1 = col[j + 1], c2 = col[j + 2];
    float v0 = value[j], v1 = value[j + 1], v2 = value[j + 2];
    const float4* x0 = (const float4*)(x + ((size_t)b * N_IN + c0) * D_IN);
    const float4* x1 = (const float4*)(x + ((size_t)b * N_IN + c1) * D_IN);
    const float4* x2 = (const float4*)(x + ((size_t)b * N_IN + c2) * D_IN);
    float4 a0 = x0[lane], a1 = x1[lane], a2 = x2[lane];
    short4v pk;
    pk[0] = (short)f2bf(v0 * a0.x + v1 * a1.x + v2 * a2.x);
    pk[1] = (short)f2bf(v0 * a0.y + v1 * a1.y + v2 * a2.y);
    pk[2] = (short)f2bf(v0 * a0.z + v1 * a1.z + v2 * a2.z);
    pk[3] = (short)f2bf(v0 * a0.w + v1 * a1.w + v2 * a2.w);
    ((short4v*)(pooled + (size_t)m * D_IN))[lane] = pk;
  } else {
    int idx = (bid - POOL_BLOCKS) * 256 + threadIdx.x;  // over 128*2304
    int o = idx / KTOT, k = idx - o * KTOT;
    Wt[idx] = f2bf(W[(size_t)k * D_OUTC + o]);
  }
}

// ---------------- kernel 2: gather-GEMM, 8 waves, 2 blocks/CU ---------------
// 512 thr = 8 waves; wave tile 32x64 (2x4 frags of 16x16), 16x16x32 MFMA.
// BK=64 (128B LDS rows, 8-chunk XOR swizzle). 2x32KB dbuf = 64KB total.
__global__ __launch_bounds__(512, 4) void gemm_kernel(
    const unsigned short* __restrict__ pooled,   // bf16 bits [MM][256]
    const unsigned short* __restrict__ Wt,       // bf16 bits [128][2304]
    const int* __restrict__ indices,
    const float* __restrict__ bias,
    float* __restrict__ out) {
  __shared__ unsigned short Asm[2][BM * BK];     // 2 x 16 KB
  __shared__ unsigned short Bsm[2][D_OUTC * BK]; // 2 x 16 KB  (64 KB total)

  const int tid = threadIdx.x;
  const int wave = tid >> 6, lane = tid & 63;
  const int wr = wave >> 1, wc = wave & 1;       // 4x2 waves of 32x64

  // XCD-aware bijective swizzle (NWG=389: q8=48, r8=5)
  const int xcd = blockIdx.x & 7, loc = blockIdx.x >> 3;
  const int q8 = NWG >> 3, r8 = NWG & 7;
  const int wg = (xcd < r8 ? xcd * (q8 + 1) : r8 * (q8 + 1) + (xcd - r8) * q8) + loc;
  const int bm = wg * BM;

  // staging geometry: 2 instrs each for A and B; instr i covers 64 rows
  // r = i*64 + (tid>>3); 8 threads/row, chunk (tid&7) of 8x16B = 128B row.
  const int srow = tid >> 3;                     // 0..63
  const int sc = ((tid & 7) ^ (srow & 7)) * 8;   // swizzled source chunk (elems)
  int nn[2]; size_t gb[2];
  const unsigned short* wtrow[2];
  #pragma unroll
  for (int i = 0; i < 2; ++i) {
    int r = i * 64 + srow;                       // 0..127
    int m = bm + r;
    int b = (unsigned)m / N_OUT;
    nn[i] = m - b * N_OUT;
    gb[i] = (size_t)b * N_OUT;
    wtrow[i] = Wt + (size_t)r * KTOT + sc;       // B row o == r
  }
  char* AsmB = (char*)&Asm[0][0];
  char* BsmB = (char*)&Bsm[0][0];

  // spiral gather indices, current + next
  int gc[2], gn[2];
  #pragma unroll
  for (int i = 0; i < 2; ++i) gc[i] = indices[nn[i] * NS + 0];

  f32x4 acc[2][4];
  #pragma unroll
  for (int i = 0; i < 2; ++i)
    #pragma unroll
    for (int j = 0; j < 4; ++j) acc[i][j] = f32x4{0.f, 0.f, 0.f, 0.f};

  // stage phase (s, q) into buffer buf
  auto stage = [&](int buf, int s, int q, const int* g) {
    const int bofs = buf * 16384;
    const int kq = s * 256 + q * 64;             // global k base for B
    #pragma unroll
    for (int i = 0; i < 2; ++i) {
      const unsigned short* srcA =
          pooled + (((gb[i] + (size_t)g[i]) << 8) + q * 64 + sc);
      gload16(srcA, AsmB + bofs + i * 8192 + tid * 16);
      gload16(wtrow[i] + kq, BsmB + bofs + i * 8192 + tid * 16);
    }
  };

  auto compute = [&](int buf) {
    const char* Ab = AsmB + buf * 16384;
    const char* Bb = BsmB + buf * 16384;
    #pragma unroll
    for (int h = 0; h < 2; ++h) {
      short8 af[2], bf[4];
      const int cb = h * 64 + (lane >> 4) * 16;  // byte col within 128B row
      #pragma unroll
      for (int i = 0; i < 2; ++i) {
        int r = wr * 32 + i * 16 + (lane & 15);
        af[i] = *(const short8*)(Ab + r * 128 + (cb ^ ((r & 7) << 4)));
      }
      #pragma unroll
      for (int j = 0; j < 4; ++j) {
        int o = wc * 64 + j * 16 + (lane & 15);
        bf[j] = *(const short8*)(Bb + o * 128 + (cb ^ ((o & 7) << 4)));
      }
      __builtin_amdgcn_s_setprio(1);
      #pragma unroll
      for (int i = 0; i < 2; ++i)
        #pragma unroll
        for (int j = 0; j < 4; ++j)
          acc[i][j] = __builtin_amdgcn_mfma_f32_16x16x32_bf16(
              af[i], bf[j], acc[i][j], 0, 0, 0);
      __builtin_amdgcn_s_setprio(0);
    }
  };

  // ---- pipeline over 36 phases (9 spirals x 4 quarters), R2-proven ---------
  stage(0, 0, 0, gc);
  __syncthreads();

  for (int s = 0; s < NS; ++s) {
    #pragma unroll
    for (int q = 0; q < 4; ++q) {
      int buf = (s * 4 + q) & 1;
      if (q == 0 && s < NS - 1) {
        #pragma unroll
        for (int i = 0; i < 2; ++i) gn[i] = indices[nn[i] * NS + s + 1];
      }
      if (q < 3)            stage(buf ^ 1, s, q + 1, gc);
      else if (s < NS - 1)  stage(buf ^ 1, s + 1, 0, gn);
      compute(buf);
      __syncthreads();   // drains vmcnt(0); cross-block TLP hides the stall
    }
    #pragma unroll
    for (int i = 0; i < 2; ++i) gc[i] = gn[i];
  }

  // ---- epilogue: bias + relu ----
  #pragma unroll
  for (int j = 0; j < 4; ++j) {
    int colo = wc * 64 + j * 16 + (lane & 15);
    float bo = bias[colo];
    #pragma unroll
    for (int i = 0; i < 2; ++i) {
      int rb = bm + wr * 32 + i * 16 + (lane >> 4) * 4;
      #pragma unroll
      for (int q = 0; q < 4; ++q) {
        int row = rb + q;
        out[(size_t)row * D_OUTC + colo] = fmaxf(acc[i][j][q] + bo, 0.f);
      }
    }
  }
}

extern "C" void kernel_launch(void* const* d_in, const int* in_sizes, int n_in,
                              void* d_out, int out_size, void* d_ws, size_t ws_size,
                              hipStream_t stream) {
  const float* x       = (const float*)d_in[0];
  // d_in[1] = row (unused: structure is repeat(arange(N_out),3))
  const int*   col     = (const int*)d_in[2];
  const float* value   = (const float*)d_in[3];
  const int*   indices = (const int*)d_in[4];
  const float* W       = (const float*)d_in[5];
  const float* bias    = (const float*)d_in[6];
  float* out           = (float*)d_out;

  unsigned short* pooled = (unsigned short*)d_ws;
  unsigned short* Wt = (unsigned short*)((char*)d_ws + (size_t)MM * D_IN * 2);

  prep_kernel<<<POOL_BLOCKS + WT_BLOCKS, 256, 0, stream>>>(x, col, value, W,
                                                           pooled, Wt);
  gemm_kernel<<<NWG, 512, 0, stream>>>(pooled, Wt, indices, bias, out);
}